// Round 17
// baseline (398.623 us; speedup 1.0000x reference)
//
#include <hip/hip_runtime.h>
#include <math.h>

#define N_TOK 32768
#define M_EMB 1024
#define D_DIM 128

// workspace layout (bytes)
#define WS_EH  0                        // bf16 e_hi[1024][128]   (256 KB)
#define WS_EL  262144                   // bf16 e_lo[1024][128]   (256 KB)
#define WS_PVG 524288                   // bf16 pvg[128][2048]    (512 KB) {hi4,lo4}/group
#define WS_E2  1048576                  // float e2[1024]
#define WS_CNT (WS_E2 + 4096)           // int counts[1024]
#define WS_SS  (WS_CNT + 4096)          // float sum((x-q)^2)
#define WS_ENT (WS_SS + 4)              // float sum(p*logp)
#define WS_DONE (WS_ENT + 4)            // int: blocks-finished counter

typedef float  f32x4  __attribute__((ext_vector_type(4)));
typedef short  s16x8  __attribute__((ext_vector_type(8)));
typedef short  s16x4  __attribute__((ext_vector_type(4)));
typedef __bf16 bf16x8 __attribute__((ext_vector_type(8)));

__device__ __forceinline__ ushort f2bf(float f) {
    unsigned x = __float_as_uint(f);
    unsigned r = (x + 0x7fffu + ((x >> 16) & 1u)) >> 16;
    return (ushort)r;
}
__device__ __forceinline__ float bf2f(ushort h) {
    return __uint_as_float(((unsigned)h) << 16);
}
__device__ __forceinline__ f32x4 mfma_k32(s16x8 a, s16x8 b, f32x4 c) {
    return __builtin_amdgcn_mfma_f32_16x16x32_bf16(
        __builtin_bit_cast(bf16x8, a), __builtin_bit_cast(bf16x8, b), c, 0, 0, 0);
}
__device__ __forceinline__ f32x4 mfma_k16(s16x4 a, s16x4 b, f32x4 c) {
#if __has_builtin(__builtin_amdgcn_mfma_f32_16x16x16bf16_1k)
    return __builtin_amdgcn_mfma_f32_16x16x16bf16_1k(a, b, c, 0, 0, 0);
#else
    asm("v_mfma_f32_16x16x16_bf16 %0, %1, %2, %0" : "+v"(c) : "v"(a), "v"(b));
    return c;
#endif
}
// async global->LDS, 16B per lane; LDS dest = uniform base + lane*16 (linear)
__device__ __forceinline__ void gl_lds16(const void* g, void* l) {
    __builtin_amdgcn_global_load_lds(
        (const __attribute__((address_space(1))) unsigned int*)g,
        (__attribute__((address_space(3))) unsigned int*)l, 16, 0, 0);
}

// Convert embedding to bf16 hi/lo (row-major, QK source) and pvg (PV source,
// {hi4,lo4}-interleaved per 4-m group, [d][2048] shorts); e2; zero accums.
__global__ void k_prep(const float* __restrict__ emb, char* ws) {
    __shared__ ushort th_s[16][128];
    __shared__ ushort tl_s[16][128];
    if (blockIdx.x == 0) {
        int* cnt = (int*)(ws + WS_CNT);
        for (int i = threadIdx.x; i < M_EMB; i += 256) cnt[i] = 0;
        if (threadIdx.x == 0) {
            *(float*)(ws + WS_SS) = 0.f;
            *(float*)(ws + WS_ENT) = 0.f;
            *(int*)(ws + WS_DONE) = 0;
        }
    }
    ushort* eh = (ushort*)(ws + WS_EH);
    ushort* el = (ushort*)(ws + WS_EL);
    ushort* pvg = (ushort*)(ws + WS_PVG);
    float* e2 = (float*)(ws + WS_E2);
    const int m0 = blockIdx.x * 16;
    const int t = threadIdx.x;
    #pragma unroll
    for (int ii = 0; ii < 8; ii++) {
        int idx = t + ii * 256;          // 0..2047
        int mi = idx >> 7, k = idx & 127;
        float v = emb[(size_t)(m0 + mi) * D_DIM + k];
        ushort hi = f2bf(v);
        ushort lo = f2bf(v - bf2f(hi));
        eh[(size_t)(m0 + mi) * D_DIM + k] = hi;
        el[(size_t)(m0 + mi) * D_DIM + k] = lo;
        th_s[mi][k] = hi;
        tl_s[mi][k] = lo;
    }
    __syncthreads();
    {
        const int d = t >> 1;
        const int gl2 = t & 1;
        #pragma unroll
        for (int gg = 0; gg < 2; gg++) {
            const int gl = gl2 * 2 + gg;         // group-within-block 0..3
            s16x8 vv;
            #pragma unroll
            for (int kk = 0; kk < 4; kk++) {
                vv[kk]     = (short)th_s[gl * 4 + kk][d];
                vv[4 + kk] = (short)tl_s[gl * 4 + kk][d];
            }
            *(s16x8*)(pvg + (size_t)d * 2048 + ((m0 >> 2) + gl) * 8) = vv;
        }
    }
    if (t < 16) {
        float s = 0.f;
        const float* er = emb + (size_t)(m0 + t) * D_DIM;
        #pragma unroll 4
        for (int k = 0; k < 128; k++) s += er[k] * er[k];
        e2[m0 + t] = s;
    }
}

// ROUND-16: occupancy was GRID-limited (16 rows/wave x full m = 2048 waves =
// 2/SIMD; rounds 13-15 show all pipes <30% busy -> latency-hiding deficit).
// New shape: 512-thread blocks = 4 pairs x 16 rows; within a pair, wave q
// streams m-half q (mc in [16q,16q+16)) -> 4096 waves = 4/SIMD. Two shared
// tile-sets (A: mc=s, B: mc=16+s), single-buffered, EXACTLY 64 KB static LDS
// (2 blocks/CU). Stats/qacc pair-merge reuses tile LDS after the loop (round-9
// proven merge logic, now 2-way). Per-wave arithmetic identical to round 15.
__global__ __launch_bounds__(512, 4) void k_main(
    const float* __restrict__ x, const float* __restrict__ emb,
    const float* __restrict__ lvq, const float* __restrict__ u,
    float* __restrict__ out, char* __restrict__ ws)
{
    __shared__ __align__(16) ushort qkh2[2][32 * 128];    // 16 KB
    __shared__ __align__(16) ushort qkl2[2][32 * 128];    // 16 KB
    __shared__ __align__(16) ushort pvt2[2][128 * 64];    // 32 KB  (total 64 KB)
    // post-loop scratch aliases (after barrier): stats+fin in pvt2, qacc in qk*
    float* sf = (float*)pvt2;     // [0)S [128)T [256)Sg [384)b1 [512)b2
                                  // [640)i1 [768)i2 [896)fin[8] [904)last_flag

    const int t = threadIdx.x;
    const int w = t >> 6;            // wave 0..7
    const int lane = t & 63;
    const int l15 = lane & 15;
    const int h = lane >> 4;
    const int p = w >> 1;            // pair 0..3 (16 rows each)
    const int q = w & 1;             // m-half of this wave
    const int rw = w & 3;            // staging role
    const int sset = w >> 2;         // staging tile-set
    const int n0p = blockIdx.x * 64 + p * 16;

    const float* e2g = (const float*)(ws + WS_E2);
    int* cnt = (int*)(ws + WS_CNT);
    float* ws_ss = (float*)(ws + WS_SS);
    float* ws_ent = (float*)(ws + WS_ENT);
    const char* EHb = (const char*)(ws + WS_EH);
    const char* ELb = (const char*)(ws + WS_EL);
    const char* PVGb = (const char*)(ws + WS_PVG);

    const float prec = expf(-lvq[0]);
    const float hp = 0.5f * prec;

    // ---- staging lane offsets (loop-invariant, swizzled global source) ----
    int offA[8];
    if (rw < 2) {
        #pragma unroll
        for (int c = 0; c < 8; c++) {
            const int s_ = c * 1024 + lane * 16;
            offA[c] = s_ ^ (((s_ >> 8) & 7) << 4);
        }
    } else {
        #pragma unroll
        for (int c = 0; c < 8; c++) {
            const int s_ = ((rw - 2) * 8 + c) * 1024 + lane * 16;
            const int d_ = s_ >> 7;
            offA[c] = d_ * 4096 + ((s_ ^ ((d_ & 7) << 4)) & 127);
        }
    }

    // ---- x B-fragments (rows n0p + l15), split hi/lo ----
    s16x8 xh[4], xl[4];
    {
        const float* xr = x + (size_t)(n0p + l15) * D_DIM;
        #pragma unroll
        for (int ks = 0; ks < 4; ks++) {
            const int k0 = ks * 32 + h * 8;
            float4 v0 = *(const float4*)(xr + k0);
            float4 v1 = *(const float4*)(xr + k0 + 4);
            float vv[8] = {v0.x, v0.y, v0.z, v0.w, v1.x, v1.y, v1.z, v1.w};
            s16x8 hi8, lo8;
            #pragma unroll
            for (int j = 0; j < 8; j++) {
                ushort hi = f2bf(vv[j]);
                hi8[j] = (short)hi;
                lo8[j] = (short)f2bf(vv[j] - bf2f(hi));
            }
            xh[ks] = hi8;
            xl[ks] = lo8;
        }
    }

    const f32x4 zz = {0.f, 0.f, 0.f, 0.f};
    f32x4 qacc[8];
    #pragma unroll
    for (int dt = 0; dt < 8; dt++) qacc[dt] = zz;

    float S = 0.f, T = 0.f, Sg = 0.f;
    float bv1 = -INFINITY, bv2 = -INFINITY;
    int bi1 = M_EMB, bi2 = M_EMB;

    const float* urow = u + (size_t)(n0p + l15) * M_EMB;
    const float EPS = 1.1920929e-07f, OME = 0.99999988f;

    #define STAGE(S_)                                                         \
        do {                                                                  \
            const int MB_ = ((sset << 4) + (S_)) << 5;                        \
            if (rw == 0) {                                                    \
                const char* src_ = EHb + (size_t)MB_ * 256;                   \
                _Pragma("unroll")                                             \
                for (int c_ = 0; c_ < 8; c_++)                                \
                    gl_lds16(src_ + offA[c_], &qkh2[sset][c_ * 512]);         \
            } else if (rw == 1) {                                             \
                const char* src_ = ELb + (size_t)MB_ * 256;                   \
                _Pragma("unroll")                                             \
                for (int c_ = 0; c_ < 8; c_++)                                \
                    gl_lds16(src_ + offA[c_], &qkl2[sset][c_ * 512]);         \
            } else {                                                          \
                const char* src_ = PVGb + (size_t)MB_ * 4;                    \
                _Pragma("unroll")                                             \
                for (int c_ = 0; c_ < 8; c_++)                                \
                    gl_lds16(src_ + offA[c_],                                 \
                             &pvt2[sset][((rw - 2) * 8 + c_) * 512]);         \
            }                                                                 \
        } while (0)

    const int Mq = (l15 & 7) << 4;   // row-swizzle mask (row&7 == l15&7)

    #pragma unroll 1
    for (int s = 0; s < 16; s++) {
        const int mc = q * 16 + s;
        const int mb = mc * 32;
        float4 uvv[2];
        #pragma unroll
        for (int t2 = 0; t2 < 2; t2++)
            uvv[t2] = *(const float4*)(urow + mb + t2 * 16 + h * 4);
        __syncthreads();             // prior step's tile reads complete
        STAGE(s);
        __syncthreads();             // drains gl_lds -> tiles resident

        #pragma unroll
        for (int t2 = 0; t2 < 2; t2++) {
            const int msub = mb + t2 * 16;
            const int r = t2 * 16 + l15;
            const char* qhB = (const char*)qkh2[q] + r * 256;
            const char* qlB = (const char*)qkl2[q] + r * 256;
            f32x4 aa = zz, ab = zz, ac = zz;
            #pragma unroll
            for (int ks = 0; ks < 4; ks++) {
                const int cb = (h * 16 + ks * 64) ^ Mq;
                const s16x8 ah = *(const s16x8*)(qhB + cb);
                const s16x8 al = *(const s16x8*)(qlB + cb);
                aa = mfma_k32(ah, xh[ks], aa);
                ab = mfma_k32(al, xh[ks], ab);
                ac = mfma_k32(ah, xl[ks], ac);
            }
            const float4 e2v = *(const float4*)(e2g + msub + h * 4);
            const float uu[4] = {uvv[t2].x, uvv[t2].y, uvv[t2].z, uvv[t2].w};
            const float ee[4] = {e2v.x, e2v.y, e2v.z, e2v.w};
            ushort pb[4];
            #pragma unroll
            for (int j = 0; j < 4; j++) {
                const int m = msub + h * 4 + j;
                const float v = prec * (aa[j] + ab[j] + ac[j]) - hp * ee[j];
                if (v > bv1) {
                    bv2 = bv1; bi2 = bi1;
                    bv1 = v; bi1 = m;
                } else if (v > bv2) {
                    bv2 = v; bi2 = m;
                }
                const float e = __expf(v);
                S += e; T += e * v;
                const float uc = fminf(fmaxf(uu[j], EPS), OME);
                const float d1 = 1.0f - uc;
                const float Lser = d1 * (1.0f + d1 * (0.5f + d1 * (0.33333334f + d1 * 0.25f)));
                const float Lnat = -__logf(uc);
                const float L = (d1 < 0.03125f) ? Lser : Lnat;
                const float pt = e * __builtin_amdgcn_rcpf(L);
                Sg += pt;
                pb[j] = f2bf(pt);
            }
            s16x4 pa;
            pa[0] = (short)pb[0]; pa[1] = (short)pb[1];
            pa[2] = (short)pb[2]; pa[3] = (short)pb[3];
            const char* pvB = (const char*)pvt2[q]
                            + ((l15 * 128 + (t2 * 4 + h) * 16) ^ Mq);
            #pragma unroll
            for (int dt = 0; dt < 8; dt++) {
                const s16x8 pv2 = *(const s16x8*)(pvB + dt * 2048);
                const s16x4 bh = __builtin_shufflevector(pv2, pv2, 0, 1, 2, 3);
                const s16x4 bl = __builtin_shufflevector(pv2, pv2, 4, 5, 6, 7);
                qacc[dt] = mfma_k16(pa, bh, qacc[dt]);
                qacc[dt] = mfma_k16(pa, bl, qacc[dt]);
            }
        }
    }
    #undef STAGE

    // ---- in-wave h-group reduce (half-m stats) ----
    #pragma unroll
    for (int off = 16; off <= 32; off <<= 1) {
        S += __shfl_xor(S, off);
        T += __shfl_xor(T, off);
        Sg += __shfl_xor(Sg, off);
        const float ov1 = __shfl_xor(bv1, off); const int oi1 = __shfl_xor(bi1, off);
        const float ov2 = __shfl_xor(bv2, off); const int oi2 = __shfl_xor(bi2, off);
        if (ov1 > bv1 || (ov1 == bv1 && oi1 < bi1)) {
            if (bv1 > ov2 || (bv1 == ov2 && bi1 < oi2)) { bv2 = bv1; bi2 = bi1; }
            else { bv2 = ov2; bi2 = oi2; }
            bv1 = ov1; bi1 = oi1;
        } else if (ov1 > bv2 || (ov1 == bv2 && oi1 < bi2)) {
            bv2 = ov1; bi2 = oi1;
        }
    }

    // ---- publish half-m stats (LDS aliases pvt2 -- need barrier first) ----
    __syncthreads();                 // all tile reads done before aliasing
    if (lane < 16) {
        sf[w * 16 + l15] = S;
        sf[128 + w * 16 + l15] = T;
        sf[256 + w * 16 + l15] = Sg;
        sf[384 + w * 16 + l15] = bv1;
        sf[512 + w * 16 + l15] = bv2;
        ((int*)sf)[640 + w * 16 + l15] = bi1;
        ((int*)sf)[768 + w * 16 + l15] = bi2;
    }
    __syncthreads();

    // ---- merge with partner wave (other m-half, same rows) ----
    {
        const int pw = w ^ 1;
        const float So = sf[pw * 16 + l15];
        const float To = sf[128 + pw * 16 + l15];
        const float Sgo = sf[256 + pw * 16 + l15];
        const float ov1 = sf[384 + pw * 16 + l15];
        const float ov2 = sf[512 + pw * 16 + l15];
        const int oi1 = ((int*)sf)[640 + pw * 16 + l15];
        const int oi2 = ((int*)sf)[768 + pw * 16 + l15];
        S += So; T += To; Sg += Sgo;
        if (ov1 > bv1 || (ov1 == bv1 && oi1 < bi1)) {
            if (bv1 > ov2 || (bv1 == ov2 && bi1 < oi2)) { bv2 = bv1; bi2 = bi1; }
            else { bv2 = ov2; bi2 = oi2; }
            bv1 = ov1; bi1 = oi1;
        } else if (ov1 > bv2 || (ov1 == bv2 && oi1 < bi2)) {
            bv2 = ov1; bi2 = oi1;
        }
    }
    float inv[4];
    #pragma unroll
    for (int j = 0; j < 4; j++)
        inv[j] = 1.0f / __shfl(Sg, 4 * h + j);

    // ---- qacc pair-merge via qk tile area (freed) ----
    float* qsc = (p < 2) ? ((float*)qkh2 + p * 2048)
                         : ((float*)qkl2 + (p - 2) * 2048);
    if (q == 1) {
        #pragma unroll
        for (int dt = 0; dt < 8; dt++)
            #pragma unroll
            for (int j = 0; j < 4; j++)
                qsc[(dt * 4 + j) * 64 + lane] = qacc[dt][j];
    }
    __syncthreads();

    if (q == 0) {
        // ---- PV epilogue (full-m qacc): out, ssl ----
        float ssl = 0.f;
        #pragma unroll
        for (int dt = 0; dt < 8; dt++) {
            #pragma unroll
            for (int j = 0; j < 4; j++) {
                const float qv = (qacc[dt][j] + qsc[(dt * 4 + j) * 64 + lane]) * inv[j];
                const int n = n0p + 4 * h + j;
                const int d = dt * 16 + l15;
                out[(size_t)n * D_DIM + d] = qv;
                const float df = x[(size_t)n * D_DIM + d] - qv;
                ssl += df * df;
            }
        }
        #pragma unroll
        for (int off = 1; off <= 32; off <<= 1) ssl += __shfl_xor(ssl, off);
        if (lane == 0) atomicAdd(ws_ss, ssl);
    } else {
        // ---- entropy (merged stats) ----
        float ent = T / S - __logf(S);
        #pragma unroll
        for (int off = 1; off <= 8; off <<= 1) ent += __shfl_xor(ent, off);
        if (lane == 0) atomicAdd(ws_ent, ent);
        // ---- exact fp32 recheck of merged top-2; write indices ----
        const float* xr = x + (size_t)(n0p + l15) * D_DIM + h * 32;
        const float* ea = emb + (size_t)bi1 * D_DIM + h * 32;
        const float* eb = emb + (size_t)bi2 * D_DIM + h * 32;
        float s1 = 0.f, s2 = 0.f;
        #pragma unroll
        for (int i = 0; i < 8; i++) {
            const float4 xv = ((const float4*)xr)[i];
            const float4 av = ((const float4*)ea)[i];
            const float4 bb = ((const float4*)eb)[i];
            s1 += xv.x * av.x + xv.y * av.y + xv.z * av.z + xv.w * av.w;
            s2 += xv.x * bb.x + xv.y * bb.y + xv.z * bb.z + xv.w * bb.w;
        }
        #pragma unroll
        for (int off = 16; off <= 32; off <<= 1) {
            s1 += __shfl_xor(s1, off);
            s2 += __shfl_xor(s2, off);
        }
        const float g1 = prec * s1 - hp * e2g[bi1];
        const float g2 = prec * s2 - hp * e2g[bi2];
        const int win = (g2 > g1 || (g2 == g1 && bi2 < bi1)) ? bi2 : bi1;
        if (lane < 16) {
            out[(size_t)N_TOK * D_DIM + n0p + lane] = (float)win;
            atomicAdd(&cnt[win], 1);
        }
    }

    // ---- last-block finalization (fused k_final) ----
    __syncthreads();                 // all block atomics issued & drained
    int* lf = (int*)(sf + 904);
    float* fin = sf + 896;
    if (t == 0) {
        const int prev = __hip_atomic_fetch_add((int*)(ws + WS_DONE), 1,
                            __ATOMIC_ACQ_REL, __HIP_MEMORY_SCOPE_AGENT);
        *lf = (prev == (int)gridDim.x - 1);
    }
    __syncthreads();
    if (*lf) {
        float s = 0.f;
        for (int i = t; i < M_EMB; i += 512) {
            const int c = __hip_atomic_load(&cnt[i], __ATOMIC_RELAXED,
                                            __HIP_MEMORY_SCOPE_AGENT);
            const float avg = (float)c * (1.f / N_TOK);
            s += avg * logf(avg + 1e-10f);
        }
        #pragma unroll
        for (int off = 32; off >= 1; off >>= 1) s += __shfl_down(s, off);
        if ((t & 63) == 0) fin[t >> 6] = s;
        __syncthreads();
        if (t == 0) {
            float tot = 0.f;
            #pragma unroll
            for (int i = 0; i < 8; i++) tot += fin[i];
            const float perp = expf(-tot);
            const float ssv = __hip_atomic_load(ws_ss, __ATOMIC_RELAXED,
                                                __HIP_MEMORY_SCOPE_AGENT);
            const float env = __hip_atomic_load(ws_ent, __ATOMIC_RELAXED,
                                                __HIP_MEMORY_SCOPE_AGENT);
            out[(size_t)N_TOK * D_DIM + N_TOK] = hp * ssv + env;
            out[(size_t)N_TOK * D_DIM + N_TOK + 1] = perp;
        }
    }
}

extern "C" void kernel_launch(void* const* d_in, const int* in_sizes, int n_in,
                              void* d_out, int out_size, void* d_ws, size_t ws_size,
                              hipStream_t stream) {
    const float* x   = (const float*)d_in[0];
    const float* emb = (const float*)d_in[1];
    const float* lvq = (const float*)d_in[2];
    const float* u   = (const float*)d_in[3];
    float* out = (float*)d_out;
    char* ws = (char*)d_ws;
    k_prep<<<dim3(M_EMB / 16), dim3(256), 0, stream>>>(emb, ws);
    k_main<<<dim3(N_TOK / 64), dim3(512), 0, stream>>>(x, emb, lvq, u, out, ws);
}